// Round 2
// baseline (452.858 us; speedup 1.0000x reference)
//
#include <hip/hip_runtime.h>
#include <hip/hip_bf16.h>

// GAT forward: N=8192, NFEAT=512, NHID=64, NHEADS=4, NCLASS=40, alpha=0.2
// Sparse formulation (softmax mask == exact sparse softmax since exp(-9e15-m)==0).

#define N_NODES 8192
#define STRIDE  192   // padded neighbor stride; deg ~ Binom(8192,0.01)+1 ≈ 82±9, 192 is >10 sigma

typedef _Float16 f16x8 __attribute__((ext_vector_type(8)));
typedef float    f32x4 __attribute__((ext_vector_type(4)));

// ---------------------------------------------------------------- prep -----
// blocks [0,8192): adjacency row -> padded neighbor list (layout-detecting)
// blocks [8192,10240): x f32 -> f16
// blocks [10240,10304): pack W1 [4][512][64] -> B1t [256][512] f16 (B1t[n][k] = W1[h][k][j], n=h*64+j)
// blocks [10304,10368): pack Wo [256][40] -> B2t [64][256] f16 (rows >=40 zero)
__global__ __launch_bounds__(256) void prep_k(
    const float* __restrict__ x, const unsigned char* __restrict__ adjb,
    const float* __restrict__ W1, const float* __restrict__ Wo,
    _Float16* __restrict__ xh, _Float16* __restrict__ B1t, _Float16* __restrict__ B2t,
    int* __restrict__ nbr, int* __restrict__ deg)
{
    const int b = blockIdx.x;
    const int tid = threadIdx.x;
    if (b < N_NODES) {
        __shared__ int cnt;
        if (tid == 0) cnt = 0;
        __syncthreads();
        // layout detect: byte 8193 == adj[1][1] (=1, self loop) iff 1-byte layout;
        // under int32/float32 layout it is a high byte of element 2048 -> 0.
        const bool bytewise = (adjb[8193] == 1);
        if (bytewise) {
            const uint4* p = (const uint4*)(adjb + (size_t)b * N_NODES);
            #pragma unroll
            for (int q = 0; q < 2; ++q) {
                const int idx = tid + 256 * q;           // uint4 index within row
                uint4 v = p[idx];
                unsigned int ws_[4] = {v.x, v.y, v.z, v.w};
                #pragma unroll
                for (int wj = 0; wj < 4; ++wj) {
                    unsigned int u = ws_[wj];
                    if (u) {
                        #pragma unroll
                        for (int by = 0; by < 4; ++by) {
                            if ((u >> (8 * by)) & 0xFFu) {
                                int c = idx * 16 + wj * 4 + by;
                                int pos = atomicAdd(&cnt, 1);
                                if (pos < STRIDE) nbr[(size_t)b * STRIDE + pos] = c;
                            }
                        }
                    }
                }
            }
        } else {
            const int4* p = (const int4*)((const int*)(const void*)adjb + (size_t)b * N_NODES);
            #pragma unroll
            for (int q = 0; q < 8; ++q) {
                const int idx = tid + 256 * q;           // int4 index within row
                int4 v = p[idx];
                if (v.x) { int pos = atomicAdd(&cnt, 1); if (pos < STRIDE) nbr[(size_t)b * STRIDE + pos] = idx * 4 + 0; }
                if (v.y) { int pos = atomicAdd(&cnt, 1); if (pos < STRIDE) nbr[(size_t)b * STRIDE + pos] = idx * 4 + 1; }
                if (v.z) { int pos = atomicAdd(&cnt, 1); if (pos < STRIDE) nbr[(size_t)b * STRIDE + pos] = idx * 4 + 2; }
                if (v.w) { int pos = atomicAdd(&cnt, 1); if (pos < STRIDE) nbr[(size_t)b * STRIDE + pos] = idx * 4 + 3; }
            }
        }
        __syncthreads();
        if (tid == 0) deg[b] = (cnt < STRIDE) ? cnt : STRIDE;
    } else if (b < N_NODES + 2048) {
        const size_t base = (size_t)(b - N_NODES) * 2048 + (size_t)tid * 8;
        float4 v0 = *(const float4*)(x + base);
        float4 v1 = *(const float4*)(x + base + 4);
        f16x8 o;
        o[0] = (_Float16)v0.x; o[1] = (_Float16)v0.y; o[2] = (_Float16)v0.z; o[3] = (_Float16)v0.w;
        o[4] = (_Float16)v1.x; o[5] = (_Float16)v1.y; o[6] = (_Float16)v1.z; o[7] = (_Float16)v1.w;
        *(f16x8*)(xh + base) = o;
    } else if (b < N_NODES + 2048 + 64) {
        const int e0 = (b - (N_NODES + 2048)) * 2048 + tid * 8;
        const int n = e0 >> 9;          // 0..255
        const int k0 = e0 & 511;
        const int h = n >> 6, j = n & 63;
        const float* src = W1 + (size_t)h * 32768 + j;     // + k*64
        f16x8 o;
        #pragma unroll
        for (int r = 0; r < 8; ++r) o[r] = (_Float16)src[(size_t)(k0 + r) * 64];
        *(f16x8*)(B1t + e0) = o;
    } else {
        const int e = (b - (N_NODES + 2048 + 64)) * 256 + tid;
        const int n = e >> 8, k = e & 255;
        B2t[e] = (n < 40) ? (_Float16)Wo[(size_t)k * 40 + n] : (_Float16)0.0f;
    }
}

// ---------------------------------------------------------------- GEMM -----
// C[M,NTOT] = A[M,KTOT] * Bt[NTOT,KTOT]^T, f16 in, f16 out (f32 accum via MFMA)
// mfma_f32_16x16x32_f16: lane l holds A[l&15][(l>>4)*8+i], B[(l>>4)*8+i][l&15],
//                        D[(l>>4)*4+r][l&15]
template<int BM, int BN, int BK, int WR, int WC, int KTOT>
__global__ __launch_bounds__(256) void gemm_k(
    const _Float16* __restrict__ A, const _Float16* __restrict__ Bt,
    _Float16* __restrict__ C, int NTOT)
{
    constexpr int WTM = BM / WR;      // wave tile rows
    constexpr int WTN = BN / WC;      // wave tile cols
    constexpr int MFR = WTM / 16;
    constexpr int NFR = WTN / 16;
    constexpr int CPR = BK / 8;       // 16B chunks per LDS row
    static_assert(CPR == 8, "swizzle assumes BK=64");
    __shared__ _Float16 As[BM * BK];
    __shared__ _Float16 Bs[BN * BK];
    const int tid = threadIdx.x;
    const int lane = tid & 63;
    const int wv = tid >> 6;
    const int wr = wv / WC, wc = wv % WC;
    const long brow = (long)blockIdx.x * BM;
    const long bcol = (long)blockIdx.y * BN;
    f32x4 acc[MFR][NFR] = {};

    for (int k0 = 0; k0 < KTOT; k0 += BK) {
        #pragma unroll
        for (int q = 0; q < (BM * BK / 8) / 256; ++q) {
            int cid = tid + 256 * q;
            int row = cid / CPR, cc = cid % CPR;
            f16x8 v = *(const f16x8*)(A + (brow + row) * KTOT + k0 + cc * 8);
            *(f16x8*)(As + row * BK + ((cc ^ (row & 7)) & (CPR - 1)) * 8) = v;
        }
        #pragma unroll
        for (int q = 0; q < (BN * BK / 8) / 256; ++q) {
            int cid = tid + 256 * q;
            int row = cid / CPR, cc = cid % CPR;
            f16x8 v = *(const f16x8*)(Bt + (bcol + row) * KTOT + k0 + cc * 8);
            *(f16x8*)(Bs + row * BK + ((cc ^ (row & 7)) & (CPR - 1)) * 8) = v;
        }
        __syncthreads();
        #pragma unroll
        for (int kk = 0; kk < BK; kk += 32) {
            f16x8 af[MFR], bf[NFR];
            #pragma unroll
            for (int m = 0; m < MFR; ++m) {
                int row = wr * WTM + m * 16 + (lane & 15);
                int cc = (kk >> 3) + (lane >> 4);
                af[m] = *(const f16x8*)(As + row * BK + ((cc ^ (row & 7)) & (CPR - 1)) * 8);
            }
            #pragma unroll
            for (int n = 0; n < NFR; ++n) {
                int row = wc * WTN + n * 16 + (lane & 15);
                int cc = (kk >> 3) + (lane >> 4);
                bf[n] = *(const f16x8*)(Bs + row * BK + ((cc ^ (row & 7)) & (CPR - 1)) * 8);
            }
            #pragma unroll
            for (int m = 0; m < MFR; ++m)
                #pragma unroll
                for (int n = 0; n < NFR; ++n)
                    acc[m][n] = __builtin_amdgcn_mfma_f32_16x16x32_f16(af[m], bf[n], acc[m][n], 0, 0, 0);
        }
        __syncthreads();
    }
    #pragma unroll
    for (int m = 0; m < MFR; ++m)
        #pragma unroll
        for (int n = 0; n < NFR; ++n)
            #pragma unroll
            for (int r = 0; r < 4; ++r) {
                long row = brow + wr * WTM + m * 16 + (lane >> 4) * 4 + r;
                long col = bcol + wc * WTN + n * 16 + (lane & 15);
                C[row * NTOT + col] = (_Float16)acc[m][n][r];
            }
}

// --------------------------------------------------------------- fsd1 ------
__global__ __launch_bounds__(256) void fsd1_k(
    const _Float16* __restrict__ Wh, const float* __restrict__ a1,
    float* __restrict__ fs, float* __restrict__ fd)
{
    const int i = blockIdx.x;
    const int h = threadIdx.x >> 6, j = threadIdx.x & 63;
    float v = (float)Wh[(size_t)i * 256 + h * 64 + j];
    float s = v * a1[h * 128 + j];
    float d = v * a1[h * 128 + 64 + j];
    #pragma unroll
    for (int o = 32; o; o >>= 1) { s += __shfl_xor(s, o); d += __shfl_xor(d, o); }
    if (j == 0) { fs[h * N_NODES + i] = s; fd[h * N_NODES + i] = d; }
}

// --------------------------------------------------------------- agg1 ------
// block per node, wave per head: softmax over neighbors + weighted Wh gather, elu -> x1 (f16)
__global__ __launch_bounds__(256) void agg1_k(
    const int* __restrict__ nbr, const int* __restrict__ deg,
    const _Float16* __restrict__ Wh, const float* __restrict__ fs,
    const float* __restrict__ fd, _Float16* __restrict__ x1)
{
    const int i = blockIdx.x;
    const int h = threadIdx.x >> 6, lane = threadIdx.x & 63;
    __shared__ float satt[4][STRIDE];
    __shared__ int scol[STRIDE];
    const int d = deg[i];
    const float fsi = fs[h * N_NODES + i];
    float e0 = -1e30f, e1 = -1e30f, e2 = -1e30f;
    int c0 = 0, c1 = 0, c2 = 0;
    if (lane < d)       { c0 = nbr[(size_t)i * STRIDE + lane];       float t = fsi + fd[h * N_NODES + c0]; e0 = t > 0.f ? t : 0.2f * t; }
    if (lane + 64 < d)  { c1 = nbr[(size_t)i * STRIDE + lane + 64];  float t = fsi + fd[h * N_NODES + c1]; e1 = t > 0.f ? t : 0.2f * t; }
    if (lane + 128 < d) { c2 = nbr[(size_t)i * STRIDE + lane + 128]; float t = fsi + fd[h * N_NODES + c2]; e2 = t > 0.f ? t : 0.2f * t; }
    float mx = fmaxf(e0, fmaxf(e1, e2));
    #pragma unroll
    for (int o = 32; o; o >>= 1) mx = fmaxf(mx, __shfl_xor(mx, o));
    float w0 = (lane < d)       ? __expf(e0 - mx) : 0.f;
    float w1 = (lane + 64 < d)  ? __expf(e1 - mx) : 0.f;
    float w2 = (lane + 128 < d) ? __expf(e2 - mx) : 0.f;
    float s = w0 + w1 + w2;
    #pragma unroll
    for (int o = 32; o; o >>= 1) s += __shfl_xor(s, o);
    const float inv = 1.f / s;
    if (lane < d)       satt[h][lane] = w0 * inv;
    if (lane + 64 < d)  satt[h][lane + 64] = w1 * inv;
    if (lane + 128 < d) satt[h][lane + 128] = w2 * inv;
    if (h == 0) {
        if (lane < d)       scol[lane] = c0;
        if (lane + 64 < d)  scol[lane + 64] = c1;
        if (lane + 128 < d) scol[lane + 128] = c2;
    }
    __syncthreads();
    // unroll x8: 8 independent gathers in flight to break the ~250cy/iter latency chain
    const _Float16* wp = Wh + h * 64 + lane;
    float a0 = 0.f, a1_ = 0.f, a2 = 0.f, a3 = 0.f, a4 = 0.f, a5 = 0.f, a6 = 0.f, a7 = 0.f;
    int t = 0;
    for (; t + 8 <= d; t += 8) {
        int s0 = scol[t], s1 = scol[t+1], s2 = scol[t+2], s3 = scol[t+3];
        int s4 = scol[t+4], s5 = scol[t+5], s6 = scol[t+6], s7 = scol[t+7];
        float g0 = (float)wp[(size_t)s0 * 256]; float g1 = (float)wp[(size_t)s1 * 256];
        float g2 = (float)wp[(size_t)s2 * 256]; float g3 = (float)wp[(size_t)s3 * 256];
        float g4 = (float)wp[(size_t)s4 * 256]; float g5 = (float)wp[(size_t)s5 * 256];
        float g6 = (float)wp[(size_t)s6 * 256]; float g7 = (float)wp[(size_t)s7 * 256];
        a0 += satt[h][t]   * g0; a1_ += satt[h][t+1] * g1;
        a2 += satt[h][t+2] * g2; a3 += satt[h][t+3] * g3;
        a4 += satt[h][t+4] * g4; a5 += satt[h][t+5] * g5;
        a6 += satt[h][t+6] * g6; a7 += satt[h][t+7] * g7;
    }
    for (; t < d; ++t) a0 += satt[h][t] * (float)wp[(size_t)scol[t] * 256];
    float acc = ((a0 + a1_) + (a2 + a3)) + ((a4 + a5) + (a6 + a7));
    float o = acc > 0.f ? acc : expm1f(acc);
    x1[(size_t)i * 256 + h * 64 + lane] = (_Float16)o;
}

// --------------------------------------------------------------- fsd2 ------
__global__ __launch_bounds__(256) void fsd2_k(
    const _Float16* __restrict__ Who, const float* __restrict__ ao,
    float* __restrict__ fso, float* __restrict__ fdo)
{
    const int wv = threadIdx.x >> 6, lane = threadIdx.x & 63;
    const int i = blockIdx.x * 4 + wv;
    float v = (lane < 40) ? (float)Who[(size_t)i * 64 + lane] : 0.f;
    float s = (lane < 40) ? v * ao[lane] : 0.f;
    float d = (lane < 40) ? v * ao[40 + lane] : 0.f;
    #pragma unroll
    for (int o = 32; o; o >>= 1) { s += __shfl_xor(s, o); d += __shfl_xor(d, o); }
    if (lane == 0) { fso[i] = s; fdo[i] = d; }
}

// --------------------------------------------------------------- agg2 ------
__global__ __launch_bounds__(256) void agg2_k(
    const int* __restrict__ nbr, const int* __restrict__ deg,
    const _Float16* __restrict__ Who, const float* __restrict__ fso,
    const float* __restrict__ fdo, float* __restrict__ out)
{
    const int wv = threadIdx.x >> 6, lane = threadIdx.x & 63;
    const int i = blockIdx.x * 4 + wv;
    __shared__ float satt[4][STRIDE];
    __shared__ int scol[4][STRIDE];
    const int d = deg[i];
    const float fsi = fso[i];
    float e0 = -1e30f, e1 = -1e30f, e2 = -1e30f;
    int c0 = 0, c1 = 0, c2 = 0;
    if (lane < d)       { c0 = nbr[(size_t)i * STRIDE + lane];       float t = fsi + fdo[c0]; e0 = t > 0.f ? t : 0.2f * t; }
    if (lane + 64 < d)  { c1 = nbr[(size_t)i * STRIDE + lane + 64];  float t = fsi + fdo[c1]; e1 = t > 0.f ? t : 0.2f * t; }
    if (lane + 128 < d) { c2 = nbr[(size_t)i * STRIDE + lane + 128]; float t = fsi + fdo[c2]; e2 = t > 0.f ? t : 0.2f * t; }
    float mx = fmaxf(e0, fmaxf(e1, e2));
    #pragma unroll
    for (int o = 32; o; o >>= 1) mx = fmaxf(mx, __shfl_xor(mx, o));
    float w0 = (lane < d)       ? __expf(e0 - mx) : 0.f;
    float w1 = (lane + 64 < d)  ? __expf(e1 - mx) : 0.f;
    float w2 = (lane + 128 < d) ? __expf(e2 - mx) : 0.f;
    float s = w0 + w1 + w2;
    #pragma unroll
    for (int o = 32; o; o >>= 1) s += __shfl_xor(s, o);
    const float inv = 1.f / s;
    if (lane < d)       { satt[wv][lane] = w0 * inv;       scol[wv][lane] = c0; }
    if (lane + 64 < d)  { satt[wv][lane + 64] = w1 * inv;  scol[wv][lane + 64] = c1; }
    if (lane + 128 < d) { satt[wv][lane + 128] = w2 * inv; scol[wv][lane + 128] = c2; }
    __syncthreads();
    float a0 = 0.f, a1_ = 0.f, a2 = 0.f, a3 = 0.f, a4 = 0.f, a5 = 0.f, a6 = 0.f, a7 = 0.f;
    int t = 0;
    for (; t + 8 <= d; t += 8) {
        int s0 = scol[wv][t],   s1 = scol[wv][t+1], s2 = scol[wv][t+2], s3 = scol[wv][t+3];
        int s4 = scol[wv][t+4], s5 = scol[wv][t+5], s6 = scol[wv][t+6], s7 = scol[wv][t+7];
        float g0 = (float)Who[(size_t)s0 * 64 + lane]; float g1 = (float)Who[(size_t)s1 * 64 + lane];
        float g2 = (float)Who[(size_t)s2 * 64 + lane]; float g3 = (float)Who[(size_t)s3 * 64 + lane];
        float g4 = (float)Who[(size_t)s4 * 64 + lane]; float g5 = (float)Who[(size_t)s5 * 64 + lane];
        float g6 = (float)Who[(size_t)s6 * 64 + lane]; float g7 = (float)Who[(size_t)s7 * 64 + lane];
        a0 += satt[wv][t]   * g0; a1_ += satt[wv][t+1] * g1;
        a2 += satt[wv][t+2] * g2; a3 += satt[wv][t+3] * g3;
        a4 += satt[wv][t+4] * g4; a5 += satt[wv][t+5] * g5;
        a6 += satt[wv][t+6] * g6; a7 += satt[wv][t+7] * g7;
    }
    for (; t < d; ++t) a0 += satt[wv][t] * (float)Who[(size_t)scol[wv][t] * 64 + lane];
    float acc = ((a0 + a1_) + (a2 + a3)) + ((a4 + a5) + (a6 + a7));
    float v = acc > 0.f ? acc : expm1f(acc);
    float vm = (lane < 40) ? v : -1e30f;
    #pragma unroll
    for (int o = 32; o; o >>= 1) vm = fmaxf(vm, __shfl_xor(vm, o));
    float ex = (lane < 40) ? __expf(v - vm) : 0.f;
    #pragma unroll
    for (int o = 32; o; o >>= 1) ex += __shfl_xor(ex, o);
    if (lane < 40) out[(size_t)i * 40 + lane] = v - vm - __logf(ex);
}

// ------------------------------------------------------------- launch ------
extern "C" void kernel_launch(void* const* d_in, const int* in_sizes, int n_in,
                              void* d_out, int out_size, void* d_ws, size_t ws_size,
                              hipStream_t stream) {
    (void)in_sizes; (void)n_in; (void)out_size; (void)ws_size;
    const float* x = (const float*)d_in[0];
    const unsigned char* adjb = (const unsigned char*)d_in[1];
    const float* W1 = (const float*)d_in[2];
    const float* a1 = (const float*)d_in[3];
    const float* Wo = (const float*)d_in[4];
    const float* ao = (const float*)d_in[5];
    float* out = (float*)d_out;

    char* w = (char*)d_ws;
    size_t off = 0;
    auto alloc = [&](size_t bytes) -> void* {
        off = (off + 255) & ~(size_t)255;
        void* p = w + off; off += bytes; return p;
    };
    _Float16* xh  = (_Float16*)alloc((size_t)N_NODES * 512 * 2);
    _Float16* B1t = (_Float16*)alloc(256 * 512 * 2);
    _Float16* B2t = (_Float16*)alloc(64 * 256 * 2);
    _Float16* Wh  = (_Float16*)alloc((size_t)N_NODES * 256 * 2);
    _Float16* x1  = (_Float16*)alloc((size_t)N_NODES * 256 * 2);
    _Float16* Who = (_Float16*)alloc((size_t)N_NODES * 64 * 2);
    float* fs1 = (float*)alloc(4 * N_NODES * 4);
    float* fd1 = (float*)alloc(4 * N_NODES * 4);
    float* fso = (float*)alloc(N_NODES * 4);
    float* fdo = (float*)alloc(N_NODES * 4);
    int* nbr = (int*)alloc((size_t)N_NODES * STRIDE * 4);
    int* deg = (int*)alloc(N_NODES * 4);

    prep_k<<<dim3(N_NODES + 2048 + 64 + 64), dim3(256), 0, stream>>>(x, adjb, W1, Wo, xh, B1t, B2t, nbr, deg);
    gemm_k<64, 64, 64, 2, 2, 512><<<dim3(128, 4), dim3(256), 0, stream>>>(xh, B1t, Wh, 256);
    fsd1_k<<<dim3(N_NODES), dim3(256), 0, stream>>>(Wh, a1, fs1, fd1);
    agg1_k<<<dim3(N_NODES), dim3(256), 0, stream>>>(nbr, deg, Wh, fs1, fd1, x1);
    gemm_k<32, 64, 64, 2, 2, 256><<<dim3(256, 1), dim3(256), 0, stream>>>(x1, B2t, Who, 64);
    fsd2_k<<<dim3(N_NODES / 4), dim3(256), 0, stream>>>(Who, ao, fso, fdo);
    agg2_k<<<dim3(N_NODES / 4), dim3(256), 0, stream>>>(nbr, deg, Who, fso, fdo, out);
}

// Round 3
// 445.233 us; speedup vs baseline: 1.0171x; 1.0171x over previous
//
#include <hip/hip_runtime.h>
#include <hip/hip_bf16.h>

// GAT forward: N=8192, NFEAT=512, NHID=64, NHEADS=4, NCLASS=40, alpha=0.2
// Sparse formulation (softmax mask == exact sparse softmax since exp(-9e15-m)==0).
// R3: drop xh pass (convert f32->f16 in gemm1 staging), fuse fs/fd epilogues
// into the GEMMs. 5 dispatches: prep, gemm1+fsd1, agg1, gemm2+fsd2, agg2.

#define N_NODES 8192
#define STRIDE  192   // padded neighbor stride; deg ~ Binom(8192,0.01)+1 ≈ 82±9, 192 is >10 sigma

typedef _Float16 f16x8 __attribute__((ext_vector_type(8)));
typedef float    f32x4 __attribute__((ext_vector_type(4)));

// ---------------------------------------------------------------- prep -----
// blocks [0,8192): adjacency row -> padded neighbor list (layout-detecting)
// blocks [8192,8256): pack W1 [4][512][64] -> B1t [256][512] f16 (B1t[n][k]=W1[h][k][j], n=h*64+j)
// blocks [8256,8320): pack Wo [256][40] -> B2t [64][256] f16 (rows >=40 zero)
__global__ __launch_bounds__(256) void prep_k(
    const unsigned char* __restrict__ adjb,
    const float* __restrict__ W1, const float* __restrict__ Wo,
    _Float16* __restrict__ B1t, _Float16* __restrict__ B2t,
    int* __restrict__ nbr, int* __restrict__ deg)
{
    const int b = blockIdx.x;
    const int tid = threadIdx.x;
    if (b < N_NODES) {
        __shared__ int cnt;
        if (tid == 0) cnt = 0;
        __syncthreads();
        // layout detect: byte 8193 == adj[1][1] (=1, self loop) iff 1-byte layout;
        // under int32/float32 layout it is a high byte of element 2048 -> 0.
        const bool bytewise = (adjb[8193] == 1);
        if (bytewise) {
            const uint4* p = (const uint4*)(adjb + (size_t)b * N_NODES);
            #pragma unroll
            for (int q = 0; q < 2; ++q) {
                const int idx = tid + 256 * q;           // uint4 index within row
                uint4 v = p[idx];
                unsigned int ws_[4] = {v.x, v.y, v.z, v.w};
                #pragma unroll
                for (int wj = 0; wj < 4; ++wj) {
                    unsigned int u = ws_[wj];
                    if (u) {
                        #pragma unroll
                        for (int by = 0; by < 4; ++by) {
                            if ((u >> (8 * by)) & 0xFFu) {
                                int c = idx * 16 + wj * 4 + by;
                                int pos = atomicAdd(&cnt, 1);
                                if (pos < STRIDE) nbr[(size_t)b * STRIDE + pos] = c;
                            }
                        }
                    }
                }
            }
        } else {
            const int4* p = (const int4*)((const int*)(const void*)adjb + (size_t)b * N_NODES);
            #pragma unroll
            for (int q = 0; q < 8; ++q) {
                const int idx = tid + 256 * q;           // int4 index within row
                int4 v = p[idx];
                if (v.x) { int pos = atomicAdd(&cnt, 1); if (pos < STRIDE) nbr[(size_t)b * STRIDE + pos] = idx * 4 + 0; }
                if (v.y) { int pos = atomicAdd(&cnt, 1); if (pos < STRIDE) nbr[(size_t)b * STRIDE + pos] = idx * 4 + 1; }
                if (v.z) { int pos = atomicAdd(&cnt, 1); if (pos < STRIDE) nbr[(size_t)b * STRIDE + pos] = idx * 4 + 2; }
                if (v.w) { int pos = atomicAdd(&cnt, 1); if (pos < STRIDE) nbr[(size_t)b * STRIDE + pos] = idx * 4 + 3; }
            }
        }
        __syncthreads();
        if (tid == 0) deg[b] = (cnt < STRIDE) ? cnt : STRIDE;
    } else if (b < N_NODES + 64) {
        const int e0 = (b - N_NODES) * 2048 + tid * 8;
        const int n = e0 >> 9;          // 0..255
        const int k0 = e0 & 511;
        const int h = n >> 6, j = n & 63;
        const float* src = W1 + (size_t)h * 32768 + j;     // + k*64
        f16x8 o;
        #pragma unroll
        for (int r = 0; r < 8; ++r) o[r] = (_Float16)src[(size_t)(k0 + r) * 64];
        *(f16x8*)(B1t + e0) = o;
    } else {
        const int e = (b - (N_NODES + 64)) * 256 + tid;
        const int n = e >> 8, k = e & 255;
        B2t[e] = (n < 40) ? (_Float16)Wo[(size_t)k * 40 + n] : (_Float16)0.0f;
    }
}

// ---------------------------------------------------------------- GEMM -----
// C[M,NTOT] = A[M,KTOT] * Bt[NTOT,KTOT]^T, f16 MFMA, f32 accum.
// SRC32: A is f32, converted during LDS staging.
// MODE 1: fused fs/fd epilogue, layer1 (head = blockIdx.y, avec = a1+h*128, AVN=64)
// MODE 2: fused fs/fd epilogue, layer2 (avec = ao, AVN=40)
// mfma_f32_16x16x32_f16: lane l holds A[l&15][(l>>4)*8+i], B[(l>>4)*8+i][l&15],
//                        D[(l>>4)*4+r][l&15]
template<int BM, int BN, int BK, int WR, int WC, int KTOT, bool SRC32, int MODE>
__global__ __launch_bounds__(256) void gemm_k(
    const void* __restrict__ Ap, const _Float16* __restrict__ Bt,
    _Float16* __restrict__ C, const float* __restrict__ av,
    float* __restrict__ fs, float* __restrict__ fd, int NTOT)
{
    constexpr int WTM = BM / WR;      // wave tile rows
    constexpr int WTN = BN / WC;      // wave tile cols
    constexpr int MFR = WTM / 16;
    constexpr int NFR = WTN / 16;
    constexpr int CPR = BK / 8;       // 16B chunks per LDS row
    static_assert(CPR == 8, "swizzle assumes BK=64");
    __shared__ _Float16 As[BM * BK];
    __shared__ _Float16 Bs[BN * BK];
    const int tid = threadIdx.x;
    const int lane = tid & 63;
    const int wv = tid >> 6;
    const int wr = wv / WC, wc = wv % WC;
    const long brow = (long)blockIdx.x * BM;
    const long bcol = (long)blockIdx.y * BN;
    f32x4 acc[MFR][NFR] = {};

    for (int k0 = 0; k0 < KTOT; k0 += BK) {
        #pragma unroll
        for (int q = 0; q < (BM * BK / 8) / 256; ++q) {
            int cid = tid + 256 * q;
            int row = cid / CPR, cc = cid % CPR;
            f16x8 v;
            if constexpr (SRC32) {
                const float* A32 = (const float*)Ap;
                float4 v0 = *(const float4*)(A32 + (brow + row) * KTOT + k0 + cc * 8);
                float4 v1 = *(const float4*)(A32 + (brow + row) * KTOT + k0 + cc * 8 + 4);
                v[0] = (_Float16)v0.x; v[1] = (_Float16)v0.y; v[2] = (_Float16)v0.z; v[3] = (_Float16)v0.w;
                v[4] = (_Float16)v1.x; v[5] = (_Float16)v1.y; v[6] = (_Float16)v1.z; v[7] = (_Float16)v1.w;
            } else {
                v = *(const f16x8*)((const _Float16*)Ap + (brow + row) * KTOT + k0 + cc * 8);
            }
            *(f16x8*)(As + row * BK + ((cc ^ (row & 7)) & (CPR - 1)) * 8) = v;
        }
        #pragma unroll
        for (int q = 0; q < (BN * BK / 8) / 256; ++q) {
            int cid = tid + 256 * q;
            int row = cid / CPR, cc = cid % CPR;
            f16x8 v = *(const f16x8*)(Bt + (bcol + row) * KTOT + k0 + cc * 8);
            *(f16x8*)(Bs + row * BK + ((cc ^ (row & 7)) & (CPR - 1)) * 8) = v;
        }
        __syncthreads();
        #pragma unroll
        for (int kk = 0; kk < BK; kk += 32) {
            f16x8 af[MFR], bf[NFR];
            #pragma unroll
            for (int m = 0; m < MFR; ++m) {
                int row = wr * WTM + m * 16 + (lane & 15);
                int cc = (kk >> 3) + (lane >> 4);
                af[m] = *(const f16x8*)(As + row * BK + ((cc ^ (row & 7)) & (CPR - 1)) * 8);
            }
            #pragma unroll
            for (int n = 0; n < NFR; ++n) {
                int row = wc * WTN + n * 16 + (lane & 15);
                int cc = (kk >> 3) + (lane >> 4);
                bf[n] = *(const f16x8*)(Bs + row * BK + ((cc ^ (row & 7)) & (CPR - 1)) * 8);
            }
            #pragma unroll
            for (int m = 0; m < MFR; ++m)
                #pragma unroll
                for (int n = 0; n < NFR; ++n)
                    acc[m][n] = __builtin_amdgcn_mfma_f32_16x16x32_f16(af[m], bf[n], acc[m][n], 0, 0, 0);
        }
        __syncthreads();
    }
    // C write
    #pragma unroll
    for (int m = 0; m < MFR; ++m)
        #pragma unroll
        for (int n = 0; n < NFR; ++n)
            #pragma unroll
            for (int r = 0; r < 4; ++r) {
                long row = brow + wr * WTM + m * 16 + (lane >> 4) * 4 + r;
                long col = bcol + wc * WTN + n * 16 + (lane & 15);
                C[row * NTOT + col] = (_Float16)acc[m][n][r];
            }
    // fused fs/fd epilogue: fs[row] = sum_col Wh[row,col]*avec_src[col] (block has ALL cols)
    if constexpr (MODE > 0) {
        constexpr int AVN = (MODE == 1) ? 64 : 40;
        const float* asrc = (MODE == 1) ? av + blockIdx.y * 128 : av;
        const float* adst = (MODE == 1) ? av + blockIdx.y * 128 + 64 : av + 40;
        float* fsb = (MODE == 1) ? fs + blockIdx.y * N_NODES + brow : fs + brow;
        float* fdb = (MODE == 1) ? fd + blockIdx.y * N_NODES + brow : fd + brow;
        __shared__ float sred[WC][2][BM];
        float as_[NFR], ad_[NFR];
        #pragma unroll
        for (int n = 0; n < NFR; ++n) {
            int j = wc * WTN + n * 16 + (lane & 15);
            as_[n] = (j < AVN) ? asrc[j] : 0.f;
            ad_[n] = (j < AVN) ? adst[j] : 0.f;
        }
        #pragma unroll
        for (int m = 0; m < MFR; ++m)
            #pragma unroll
            for (int r = 0; r < 4; ++r) {
                float vfs = 0.f, vfd = 0.f;
                #pragma unroll
                for (int n = 0; n < NFR; ++n) { vfs += acc[m][n][r] * as_[n]; vfd += acc[m][n][r] * ad_[n]; }
                #pragma unroll
                for (int o = 1; o < 16; o <<= 1) { vfs += __shfl_xor(vfs, o); vfd += __shfl_xor(vfd, o); }
                if ((lane & 15) == 0) {
                    int row = wr * WTM + m * 16 + (lane >> 4) * 4 + r;
                    sred[wc][0][row] = vfs; sred[wc][1][row] = vfd;
                }
            }
        __syncthreads();
        if (tid < BM) {
            float s = 0.f, dd = 0.f;
            #pragma unroll
            for (int w2 = 0; w2 < WC; ++w2) { s += sred[w2][0][tid]; dd += sred[w2][1][tid]; }
            fsb[tid] = s; fdb[tid] = dd;
        }
    }
}

// --------------------------------------------------------------- agg1 ------
// block per node, wave per head: softmax over neighbors + weighted Wh gather, elu -> x1 (f16)
__global__ __launch_bounds__(256) void agg1_k(
    const int* __restrict__ nbr, const int* __restrict__ deg,
    const _Float16* __restrict__ Wh, const float* __restrict__ fs,
    const float* __restrict__ fd, _Float16* __restrict__ x1)
{
    const int i = blockIdx.x;
    const int h = threadIdx.x >> 6, lane = threadIdx.x & 63;
    __shared__ float satt[4][STRIDE];
    __shared__ int scol[STRIDE];
    const int d = deg[i];
    const float fsi = fs[h * N_NODES + i];
    float e0 = -1e30f, e1 = -1e30f, e2 = -1e30f;
    int c0 = 0, c1 = 0, c2 = 0;
    if (lane < d)       { c0 = nbr[(size_t)i * STRIDE + lane];       float t = fsi + fd[h * N_NODES + c0]; e0 = t > 0.f ? t : 0.2f * t; }
    if (lane + 64 < d)  { c1 = nbr[(size_t)i * STRIDE + lane + 64];  float t = fsi + fd[h * N_NODES + c1]; e1 = t > 0.f ? t : 0.2f * t; }
    if (lane + 128 < d) { c2 = nbr[(size_t)i * STRIDE + lane + 128]; float t = fsi + fd[h * N_NODES + c2]; e2 = t > 0.f ? t : 0.2f * t; }
    float mx = fmaxf(e0, fmaxf(e1, e2));
    #pragma unroll
    for (int o = 32; o; o >>= 1) mx = fmaxf(mx, __shfl_xor(mx, o));
    float w0 = (lane < d)       ? __expf(e0 - mx) : 0.f;
    float w1 = (lane + 64 < d)  ? __expf(e1 - mx) : 0.f;
    float w2 = (lane + 128 < d) ? __expf(e2 - mx) : 0.f;
    float s = w0 + w1 + w2;
    #pragma unroll
    for (int o = 32; o; o >>= 1) s += __shfl_xor(s, o);
    const float inv = 1.f / s;
    if (lane < d)       satt[h][lane] = w0 * inv;
    if (lane + 64 < d)  satt[h][lane + 64] = w1 * inv;
    if (lane + 128 < d) satt[h][lane + 128] = w2 * inv;
    if (h == 0) {
        if (lane < d)       scol[lane] = c0;
        if (lane + 64 < d)  scol[lane + 64] = c1;
        if (lane + 128 < d) scol[lane + 128] = c2;
    }
    __syncthreads();
    const _Float16* wp = Wh + h * 64 + lane;
    float a0 = 0.f, a1_ = 0.f, a2 = 0.f, a3 = 0.f, a4 = 0.f, a5 = 0.f, a6 = 0.f, a7 = 0.f;
    int t = 0;
    for (; t + 8 <= d; t += 8) {
        int s0 = scol[t], s1 = scol[t+1], s2 = scol[t+2], s3 = scol[t+3];
        int s4 = scol[t+4], s5 = scol[t+5], s6 = scol[t+6], s7 = scol[t+7];
        float g0 = (float)wp[(size_t)s0 * 256]; float g1 = (float)wp[(size_t)s1 * 256];
        float g2 = (float)wp[(size_t)s2 * 256]; float g3 = (float)wp[(size_t)s3 * 256];
        float g4 = (float)wp[(size_t)s4 * 256]; float g5 = (float)wp[(size_t)s5 * 256];
        float g6 = (float)wp[(size_t)s6 * 256]; float g7 = (float)wp[(size_t)s7 * 256];
        a0 += satt[h][t]   * g0; a1_ += satt[h][t+1] * g1;
        a2 += satt[h][t+2] * g2; a3 += satt[h][t+3] * g3;
        a4 += satt[h][t+4] * g4; a5 += satt[h][t+5] * g5;
        a6 += satt[h][t+6] * g6; a7 += satt[h][t+7] * g7;
    }
    for (; t < d; ++t) a0 += satt[h][t] * (float)wp[(size_t)scol[t] * 256];
    float acc = ((a0 + a1_) + (a2 + a3)) + ((a4 + a5) + (a6 + a7));
    float o = acc > 0.f ? acc : expm1f(acc);
    x1[(size_t)i * 256 + h * 64 + lane] = (_Float16)o;
}

// --------------------------------------------------------------- agg2 ------
__global__ __launch_bounds__(256) void agg2_k(
    const int* __restrict__ nbr, const int* __restrict__ deg,
    const _Float16* __restrict__ Who, const float* __restrict__ fso,
    const float* __restrict__ fdo, float* __restrict__ out)
{
    const int wv = threadIdx.x >> 6, lane = threadIdx.x & 63;
    const int i = blockIdx.x * 4 + wv;
    __shared__ float satt[4][STRIDE];
    __shared__ int scol[4][STRIDE];
    const int d = deg[i];
    const float fsi = fso[i];
    float e0 = -1e30f, e1 = -1e30f, e2 = -1e30f;
    int c0 = 0, c1 = 0, c2 = 0;
    if (lane < d)       { c0 = nbr[(size_t)i * STRIDE + lane];       float t = fsi + fdo[c0]; e0 = t > 0.f ? t : 0.2f * t; }
    if (lane + 64 < d)  { c1 = nbr[(size_t)i * STRIDE + lane + 64];  float t = fsi + fdo[c1]; e1 = t > 0.f ? t : 0.2f * t; }
    if (lane + 128 < d) { c2 = nbr[(size_t)i * STRIDE + lane + 128]; float t = fsi + fdo[c2]; e2 = t > 0.f ? t : 0.2f * t; }
    float mx = fmaxf(e0, fmaxf(e1, e2));
    #pragma unroll
    for (int o = 32; o; o >>= 1) mx = fmaxf(mx, __shfl_xor(mx, o));
    float w0 = (lane < d)       ? __expf(e0 - mx) : 0.f;
    float w1 = (lane + 64 < d)  ? __expf(e1 - mx) : 0.f;
    float w2 = (lane + 128 < d) ? __expf(e2 - mx) : 0.f;
    float s = w0 + w1 + w2;
    #pragma unroll
    for (int o = 32; o; o >>= 1) s += __shfl_xor(s, o);
    const float inv = 1.f / s;
    if (lane < d)       { satt[wv][lane] = w0 * inv;       scol[wv][lane] = c0; }
    if (lane + 64 < d)  { satt[wv][lane + 64] = w1 * inv;  scol[wv][lane + 64] = c1; }
    if (lane + 128 < d) { satt[wv][lane + 128] = w2 * inv; scol[wv][lane + 128] = c2; }
    __syncthreads();
    float a0 = 0.f, a1_ = 0.f, a2 = 0.f, a3 = 0.f, a4 = 0.f, a5 = 0.f, a6 = 0.f, a7 = 0.f;
    int t = 0;
    for (; t + 8 <= d; t += 8) {
        int s0 = scol[wv][t],   s1 = scol[wv][t+1], s2 = scol[wv][t+2], s3 = scol[wv][t+3];
        int s4 = scol[wv][t+4], s5 = scol[wv][t+5], s6 = scol[wv][t+6], s7 = scol[wv][t+7];
        float g0 = (float)Who[(size_t)s0 * 64 + lane]; float g1 = (float)Who[(size_t)s1 * 64 + lane];
        float g2 = (float)Who[(size_t)s2 * 64 + lane]; float g3 = (float)Who[(size_t)s3 * 64 + lane];
        float g4 = (float)Who[(size_t)s4 * 64 + lane]; float g5 = (float)Who[(size_t)s5 * 64 + lane];
        float g6 = (float)Who[(size_t)s6 * 64 + lane]; float g7 = (float)Who[(size_t)s7 * 64 + lane];
        a0 += satt[wv][t]   * g0; a1_ += satt[wv][t+1] * g1;
        a2 += satt[wv][t+2] * g2; a3 += satt[wv][t+3] * g3;
        a4 += satt[wv][t+4] * g4; a5 += satt[wv][t+5] * g5;
        a6 += satt[wv][t+6] * g6; a7 += satt[wv][t+7] * g7;
    }
    for (; t < d; ++t) a0 += satt[wv][t] * (float)Who[(size_t)scol[wv][t] * 64 + lane];
    float acc = ((a0 + a1_) + (a2 + a3)) + ((a4 + a5) + (a6 + a7));
    float v = acc > 0.f ? acc : expm1f(acc);
    float vm = (lane < 40) ? v : -1e30f;
    #pragma unroll
    for (int o = 32; o; o >>= 1) vm = fmaxf(vm, __shfl_xor(vm, o));
    float ex = (lane < 40) ? __expf(v - vm) : 0.f;
    #pragma unroll
    for (int o = 32; o; o >>= 1) ex += __shfl_xor(ex, o);
    if (lane < 40) out[(size_t)i * 40 + lane] = v - vm - __logf(ex);
}

// ------------------------------------------------------------- launch ------
extern "C" void kernel_launch(void* const* d_in, const int* in_sizes, int n_in,
                              void* d_out, int out_size, void* d_ws, size_t ws_size,
                              hipStream_t stream) {
    (void)in_sizes; (void)n_in; (void)out_size; (void)ws_size;
    const float* x = (const float*)d_in[0];
    const unsigned char* adjb = (const unsigned char*)d_in[1];
    const float* W1 = (const float*)d_in[2];
    const float* a1 = (const float*)d_in[3];
    const float* Wo = (const float*)d_in[4];
    const float* ao = (const float*)d_in[5];
    float* out = (float*)d_out;

    char* w = (char*)d_ws;
    size_t off = 0;
    auto alloc = [&](size_t bytes) -> void* {
        off = (off + 255) & ~(size_t)255;
        void* p = w + off; off += bytes; return p;
    };
    _Float16* B1t = (_Float16*)alloc(256 * 512 * 2);
    _Float16* B2t = (_Float16*)alloc(64 * 256 * 2);
    _Float16* Wh  = (_Float16*)alloc((size_t)N_NODES * 256 * 2);
    _Float16* x1  = (_Float16*)alloc((size_t)N_NODES * 256 * 2);
    _Float16* Who = (_Float16*)alloc((size_t)N_NODES * 64 * 2);
    float* fs1 = (float*)alloc(4 * N_NODES * 4);
    float* fd1 = (float*)alloc(4 * N_NODES * 4);
    float* fso = (float*)alloc(N_NODES * 4);
    float* fdo = (float*)alloc(N_NODES * 4);
    int* nbr = (int*)alloc((size_t)N_NODES * STRIDE * 4);
    int* deg = (int*)alloc(N_NODES * 4);

    prep_k<<<dim3(N_NODES + 64 + 64), dim3(256), 0, stream>>>(adjb, W1, Wo, B1t, B2t, nbr, deg);
    // layer1 GEMM + fused fs/fd: A = x (f32), Bt = B1t, head = blockIdx.y
    gemm_k<64, 64, 64, 2, 2, 512, true, 1><<<dim3(128, 4), dim3(256), 0, stream>>>(
        x, B1t, Wh, a1, fs1, fd1, 256);
    agg1_k<<<dim3(N_NODES), dim3(256), 0, stream>>>(nbr, deg, Wh, fs1, fd1, x1);
    // layer2 GEMM + fused fso/fdo: A = x1 (f16), Bt = B2t
    gemm_k<32, 64, 64, 2, 2, 256, false, 2><<<dim3(256, 1), dim3(256), 0, stream>>>(
        x1, B2t, Who, ao, fso, fdo, 64);
    agg2_k<<<dim3(N_NODES / 4), dim3(256), 0, stream>>>(nbr, deg, Who, fso, fdo, out);
}